// Round 2
// baseline (1562.017 us; speedup 1.0000x reference)
//
#include <hip/hip_runtime.h>

typedef __attribute__((ext_vector_type(4))) float f32x4;
typedef __attribute__((ext_vector_type(8))) short bf16x8;
typedef __attribute__((ext_vector_type(4))) unsigned short u16x4;

// Static device intermediates (BSS, zero-init at module load; fully
// rewritten every kernel_launch -> deterministic, no d_ws dependence).
__device__ static float g_qkv[(size_t)50176 * 2304];   // (b,tok,t,768) 462 MB
__device__ static float g_g1[(size_t)48 * 784 * 256];  // (b*3+t,28*28,256) 38.5 MB
__device__ static float g_g2[(size_t)48 * 196 * 256];  // (b*3+t,14*14,256) 9.6 MB
__device__ static float g_fused[(size_t)50176 * 768];  // (b,n,768) 154 MB

static __device__ __forceinline__ unsigned short f2bf(float x){
  unsigned u = __float_as_uint(x);
  u += 0x7fffu + ((u >> 16) & 1u);
  return (unsigned short)(u >> 16);
}
static __device__ __forceinline__ float bf2f(unsigned short h){
  return __uint_as_float(((unsigned)h) << 16);
}

// C[m][n] = sum_k A[m][k] * B[n][k] (+ bias[n]); split-bf16 (hi/lo), 3 MFMAs.
// Tile 128x128, BK=32, 4 waves (2x2), each wave 64x64 via 4x4 16x16x32 frags.
template<bool BIAS>
__global__ __launch_bounds__(256)
void gemm_bt_split(const float* __restrict__ A, const float* __restrict__ Bm,
                   const float* __restrict__ bias, float* __restrict__ C,
                   int M, int N, int K)
{
  __shared__ unsigned short As_hi[128][40], As_lo[128][40];
  __shared__ unsigned short Bs_hi[128][40], Bs_lo[128][40];
  const int tid = threadIdx.x;
  const int lane = tid & 63;
  const int w = tid >> 6;
  const int wm = w >> 1, wn = w & 1;
  const int bm = blockIdx.y, bn = blockIdx.x;
  const int l15 = lane & 15, l4 = lane >> 4;

  f32x4 acc[4][4];
  #pragma unroll
  for (int i = 0; i < 4; i++)
    #pragma unroll
    for (int j = 0; j < 4; j++) acc[i][j] = (f32x4)0.f;

  const int r0 = tid >> 3;        // 0..31
  const int kv = (tid & 7) * 4;   // 0,4,...,28

  for (int kt = 0; kt < K; kt += 32) {
    __syncthreads();
    #pragma unroll
    for (int rr = 0; rr < 128; rr += 32) {
      const int row = rr + r0;
      f32x4 a4 = *(const f32x4*)&A[(size_t)(bm * 128 + row) * K + kt + kv];
      f32x4 b4 = *(const f32x4*)&Bm[(size_t)(bn * 128 + row) * K + kt + kv];
      u16x4 ah, al, bh, bl;
      #pragma unroll
      for (int j = 0; j < 4; j++) {
        unsigned short h = f2bf(a4[j]); ah[j] = h; al[j] = f2bf(a4[j] - bf2f(h));
        h = f2bf(b4[j]);               bh[j] = h; bl[j] = f2bf(b4[j] - bf2f(h));
      }
      *(u16x4*)&As_hi[row][kv] = ah;
      *(u16x4*)&As_lo[row][kv] = al;
      *(u16x4*)&Bs_hi[row][kv] = bh;
      *(u16x4*)&Bs_lo[row][kv] = bl;
    }
    __syncthreads();

    bf16x8 a_hi[4], a_lo[4], b_hi[4], b_lo[4];
    #pragma unroll
    for (int mi = 0; mi < 4; mi++) {
      const int r = wm * 64 + mi * 16 + l15;
      a_hi[mi] = *(const bf16x8*)&As_hi[r][l4 * 8];
      a_lo[mi] = *(const bf16x8*)&As_lo[r][l4 * 8];
    }
    #pragma unroll
    for (int ni = 0; ni < 4; ni++) {
      const int r = wn * 64 + ni * 16 + l15;
      b_hi[ni] = *(const bf16x8*)&Bs_hi[r][l4 * 8];
      b_lo[ni] = *(const bf16x8*)&Bs_lo[r][l4 * 8];
    }
    #pragma unroll
    for (int mi = 0; mi < 4; mi++)
      #pragma unroll
      for (int ni = 0; ni < 4; ni++) {
        acc[mi][ni] = __builtin_amdgcn_mfma_f32_16x16x32_bf16(a_hi[mi], b_hi[ni], acc[mi][ni], 0, 0, 0);
        acc[mi][ni] = __builtin_amdgcn_mfma_f32_16x16x32_bf16(a_lo[mi], b_hi[ni], acc[mi][ni], 0, 0, 0);
        acc[mi][ni] = __builtin_amdgcn_mfma_f32_16x16x32_bf16(a_hi[mi], b_lo[ni], acc[mi][ni], 0, 0, 0);
      }
  }

  #pragma unroll
  for (int mi = 0; mi < 4; mi++)
    #pragma unroll
    for (int ni = 0; ni < 4; ni++) {
      const int col = bn * 128 + wn * 64 + ni * 16 + l15;
      const float bv = BIAS ? bias[col] : 0.f;
      #pragma unroll
      for (int reg = 0; reg < 4; reg++) {
        const int row = bm * 128 + wm * 64 + mi * 16 + l4 * 4 + reg;
        C[(size_t)row * N + col] = acc[mi][ni][reg] + bv;
      }
    }
}

// Fused grouped conv3x3 (groups=64, 4in/4out per group) + bias + 2x2 maxpool.
// qkv layout: (b, tok=y*56+x, t, 768ch). Output: (b*3+t, y, x, 256ch).
__global__ __launch_bounds__(256)
void conv_pool(const float* __restrict__ qkv, const float* __restrict__ wsrc,
               const float* __restrict__ bias, float* __restrict__ gout,
               int chan0, int Pout, int st, int pd, int dl)
{
  __shared__ float wl[64 * 145];   // stride 145 (odd->conflict-free across g)
  const int g = threadIdx.x;       // 0..63
  const int ty = threadIdx.y;      // 0..3
  const int tid = ty * 64 + g;
  for (int i = tid; i < 9216; i += 256) {
    const int oc = i / 36, rem = i - oc * 36;
    wl[(oc >> 2) * 145 + (oc & 3) * 36 + rem] = wsrc[i];
  }
  __syncthreads();

  const int bt = blockIdx.x;
  const int b = bt / 3, t = bt - b * 3;
  const int total = Pout * Pout;
  const int p = blockIdx.y * 4 + ty;
  if (p >= total) return;
  const int y = p / Pout, x = p - y * Pout;

  const f32x4 bias4 = *(const f32x4*)&bias[g * 4];
  f32x4 best;
  #pragma unroll
  for (int j = 0; j < 4; j++) best[j] = -3.4e38f;
  const float* wg = &wl[g * 145];

  #pragma unroll
  for (int dy = 0; dy < 2; dy++)
    #pragma unroll
    for (int dx = 0; dx < 2; dx++) {
      const int py = 2 * y + dy, px = 2 * x + dx;
      f32x4 c4 = bias4;
      #pragma unroll
      for (int ky = 0; ky < 3; ky++) {
        const int iy = py * st - pd + ky * dl;
        if (iy < 0 || iy >= 56) continue;
        #pragma unroll
        for (int kx = 0; kx < 3; kx++) {
          const int ix = px * st - pd + kx * dl;
          if (ix < 0 || ix >= 56) continue;
          const f32x4 in4 = *(const f32x4*)&qkv[((size_t)(b * 3136 + iy * 56 + ix) * 3 + t) * 768 + chan0 + g * 4];
          #pragma unroll
          for (int oc = 0; oc < 4; oc++) {
            const float* wp = &wg[oc * 36 + ky * 3 + kx];
            c4[oc] += in4[0] * wp[0] + in4[1] * wp[9] + in4[2] * wp[18] + in4[3] * wp[27];
          }
        }
      }
      #pragma unroll
      for (int j = 0; j < 4; j++) best[j] = fmaxf(best[j], c4[j]);
    }
  *(f32x4*)&gout[((size_t)bt * total + p) * 256 + g * 4] = best;
}

// Windowed attention: one block per (b, region, head). 49x64 tiles, f32.
template<int SRC>
__global__ __launch_bounds__(256)
void attn_win(const float* __restrict__ src, float* __restrict__ fused,
              int side, int Hs, int head_base0, int rep)
{
  __shared__ float Qs[49][65], Ks[49][65], Vs[49][65], Ss[49][50];
  const int tid = threadIdx.x;
  const int nreg = side * side;
  int bid = blockIdx.x;
  const int h = bid & 3; bid >>= 2;
  const int r = bid % nreg;
  const int b = bid / nreg;
  const int hr = r / side, wr = r - hr * side;

  for (int v = tid; v < 49 * 16; v += 256) {
    const int pp = v >> 4, d0 = (v & 15) * 4;
    const int py = pp / 7, pxx = pp - py * 7;
    const int yy = hr * 7 + py, xx = wr * 7 + pxx;
    #pragma unroll
    for (int t = 0; t < 3; t++) {
      size_t idx;
      if (SRC == 0) idx = ((size_t)(b * 3136 + yy * 56 + xx) * 3 + t) * 768 + h * 64 + d0;
      else          idx = ((size_t)(b * 3 + t) * (Hs * Hs) + yy * Hs + xx) * 256 + h * 64 + d0;
      const f32x4 val = *(const f32x4*)&src[idx];
      float* dst = (t == 0) ? &Qs[pp][d0] : (t == 1) ? &Ks[pp][d0] : &Vs[pp][d0];
      dst[0] = val[0]; dst[1] = val[1]; dst[2] = val[2]; dst[3] = val[3];
    }
  }
  __syncthreads();

  for (int e = tid; e < 49 * 49; e += 256) {
    const int pp = e / 49, qq = e - pp * 49;
    float acc = 0.f;
    #pragma unroll 8
    for (int d = 0; d < 64; d++) acc += Qs[pp][d] * Ks[qq][d];
    Ss[pp][qq] = acc * 0.125f;
  }
  __syncthreads();

  if (tid < 49) {
    float mx = -3.4e38f;
    for (int qq = 0; qq < 49; qq++) mx = fmaxf(mx, Ss[tid][qq]);
    float sum = 0.f;
    for (int qq = 0; qq < 49; qq++) { const float ev = expf(Ss[tid][qq] - mx); Ss[tid][qq] = ev; sum += ev; }
    const float inv = 1.f / sum;
    for (int qq = 0; qq < 49; qq++) Ss[tid][qq] *= inv;
  }
  __syncthreads();

  const int head = head_base0 + h;
  for (int e = tid; e < 49 * 64; e += 256) {
    const int pp = e >> 6, d = e & 63;
    float acc = 0.f;
    #pragma unroll 7
    for (int qq = 0; qq < 49; qq++) acc += Ss[pp][qq] * Vs[qq][d];
    for (int m = 0; m < rep; m++) {
      const int n = (m * nreg + r) * 49 + pp;
      fused[((size_t)b * 3136 + n) * 768 + head * 64 + d] = acc;
    }
  }
}

extern "C" void kernel_launch(void* const* d_in, const int* in_sizes, int n_in,
                              void* d_out, int out_size, void* d_ws, size_t ws_size,
                              hipStream_t stream)
{
  const float* x      = (const float*)d_in[0];
  const float* w_qkv  = (const float*)d_in[1];
  const float* w_proj = (const float*)d_in[2];
  const float* b_proj = (const float*)d_in[3];
  const float* c1w    = (const float*)d_in[4];
  const float* c1b    = (const float*)d_in[5];
  const float* c2w    = (const float*)d_in[6];
  const float* c2b    = (const float*)d_in[7];
  float* out = (float*)d_out;

  float* qkv;   hipGetSymbolAddress((void**)&qkv,   HIP_SYMBOL(g_qkv));
  float* g1;    hipGetSymbolAddress((void**)&g1,    HIP_SYMBOL(g_g1));
  float* g2;    hipGetSymbolAddress((void**)&g2,    HIP_SYMBOL(g_g2));
  float* fused; hipGetSymbolAddress((void**)&fused, HIP_SYMBOL(g_fused));

  // 1) QKV GEMM: (50176,768) @ (2304,768)^T -> qkv
  gemm_bt_split<false><<<dim3(2304 / 128, 50176 / 128), 256, 0, stream>>>(
      x, w_qkv, nullptr, qkv, 50176, 2304, 768);

  // 2) convs for scales 1 and 2
  conv_pool<<<dim3(48, 196), dim3(64, 4), 0, stream>>>(qkv, c1w, c1b, g1, 256, 28, 1, 1, 1);
  conv_pool<<<dim3(48, 49),  dim3(64, 4), 0, stream>>>(qkv, c2w, c2b, g2, 512, 14, 2, 2, 2);

  // 3) windowed attention per scale -> fused
  attn_win<0><<<16 * 64 * 4, 256, 0, stream>>>(qkv, fused, 8, 56, 0, 1);
  attn_win<1><<<16 * 16 * 4, 256, 0, stream>>>(g1, fused, 4, 28, 4, 4);
  attn_win<1><<<16 * 4 * 4,  256, 0, stream>>>(g2, fused, 2, 14, 8, 16);

  // 4) proj GEMM + bias -> out
  gemm_bt_split<true><<<dim3(768 / 128, 50176 / 128), 256, 0, stream>>>(
      fused, w_proj, b_proj, out, 50176, 768, 768);
}

// Round 3
// 1047.740 us; speedup vs baseline: 1.4908x; 1.4908x over previous
//
#include <hip/hip_runtime.h>

typedef __attribute__((ext_vector_type(4))) float f32x4;
typedef __attribute__((ext_vector_type(8))) short bf16x8;
typedef __attribute__((ext_vector_type(4))) unsigned short u16x4;
typedef unsigned short u16;

// Static device intermediates (BSS; fully rewritten every launch).
__device__ static u16   g_xh[(size_t)50176 * 768];     // bf16(x)            77 MB
__device__ static u16   g_wqkvh[(size_t)2304 * 768];   // bf16(w_qkv)       3.5 MB
__device__ static u16   g_wprojh[(size_t)768 * 768];   // bf16(w_proj)      1.2 MB
__device__ static u16   g_qkv[(size_t)50176 * 2304];   // qkv bf16          231 MB
__device__ static float g_g1[(size_t)48 * 784 * 256];  // conv1 out f32    38.5 MB
__device__ static float g_g2[(size_t)48 * 196 * 256];  // conv2 out f32     9.6 MB
__device__ static u16   g_fh[(size_t)50176 * 768];     // fused hi bf16      77 MB
__device__ static u16   g_fl[(size_t)50176 * 768];     // fused lo bf16      77 MB

static __device__ __forceinline__ u16 f2bf(float x){
  unsigned u = __float_as_uint(x);
  u += 0x7fffu + ((u >> 16) & 1u);
  return (u16)(u >> 16);
}
static __device__ __forceinline__ float bf2f(u16 h){
  return __uint_as_float(((unsigned)h) << 16);
}

// f32 -> bf16 (RNE), vectorized x4, grid-stride.
__global__ __launch_bounds__(256)
void cvt_bf16(const float* __restrict__ in, u16* __restrict__ out, int n4)
{
  int i = blockIdx.x * blockDim.x + threadIdx.x;
  const int stride = gridDim.x * blockDim.x;
  for (; i < n4; i += stride) {
    const f32x4 v = ((const f32x4*)in)[i];
    u16x4 o;
    #pragma unroll
    for (int j = 0; j < 4; j++) o[j] = f2bf(v[j]);
    ((u16x4*)out)[i] = o;
  }
}

// C[m][n] = sum_k (A0[m][k] (+A1[m][k])) * B[n][k] (+ bias[n])
// A0/A1/B bf16 row-major [.][K]; 128x128 tile, BK=64, 4 waves (2x2), each wave
// 64x64 via 4x4 16x16x32 frags. global_load_lds width-16 staging with
// XOR-swizzled source (chunk c ^= row&7) and matching swizzled ds_read.
template<int PLANES, bool BIAS, typename OUT_T>
__global__ __launch_bounds__(256)
void gemm_lds(const u16* __restrict__ A0, const u16* __restrict__ A1,
              const u16* __restrict__ Bw, const float* __restrict__ bias,
              OUT_T* __restrict__ C, int N, int K)
{
  // [plane][128 rows][64 bf16]; plane p at p*16384 bytes. B at PLANES*16384.
  __shared__ __align__(16) u16 lds[(PLANES + 1) * 8192];
  char* ldsb = (char*)lds;
  const int tid = threadIdx.x;
  const int lane = tid & 63;
  const int w = tid >> 6;
  const int wm = w >> 1, wn = w & 1;
  const int bm = blockIdx.y, bn = blockIdx.x;
  const int l15 = lane & 15, l4 = lane >> 4;
  const int lr = lane >> 3;            // row within 8-row chunk
  const int cxor = (lane & 7) ^ lr;    // swizzled source 16B-chunk column

  f32x4 acc[4][4];
  #pragma unroll
  for (int i = 0; i < 4; i++)
    #pragma unroll
    for (int j = 0; j < 4; j++) acc[i][j] = (f32x4)0.f;

  const u16* aptr[2] = {A0, A1};
  const int num_chunks = (PLANES + 1) * 16;

  for (int kt = 0; kt < K; kt += 64) {
    __syncthreads();
    for (int q = w; q < num_chunks; q += 4) {
      const int plane = q >> 4, i = q & 15;
      const int row = i * 8 + lr;
      const u16* src;
      if (plane < PLANES) src = aptr[plane] + (size_t)(bm * 128 + row) * K + kt + cxor * 8;
      else                src = Bw          + (size_t)(bn * 128 + row) * K + kt + cxor * 8;
      __builtin_amdgcn_global_load_lds(
          (__attribute__((address_space(1))) const void*)src,
          (__attribute__((address_space(3))) void*)(ldsb + q * 1024),
          16, 0, 0);
    }
    __syncthreads();

    #pragma unroll
    for (int ks = 0; ks < 2; ks++) {
      bf16x8 af[PLANES][4], bfr[4];
      #pragma unroll
      for (int mi = 0; mi < 4; mi++) {
        const int row = wm * 64 + mi * 16 + l15;
        const int bo = row * 128 + (((l4 + 4 * ks) ^ (row & 7)) << 4);
        #pragma unroll
        for (int p = 0; p < PLANES; p++)
          af[p][mi] = *(const bf16x8*)(ldsb + p * 16384 + bo);
      }
      #pragma unroll
      for (int ni = 0; ni < 4; ni++) {
        const int row = wn * 64 + ni * 16 + l15;
        const int bo = row * 128 + (((l4 + 4 * ks) ^ (row & 7)) << 4);
        bfr[ni] = *(const bf16x8*)(ldsb + PLANES * 16384 + bo);
      }
      #pragma unroll
      for (int mi = 0; mi < 4; mi++)
        #pragma unroll
        for (int ni = 0; ni < 4; ni++) {
          acc[mi][ni] = __builtin_amdgcn_mfma_f32_16x16x32_bf16(af[0][mi], bfr[ni], acc[mi][ni], 0, 0, 0);
          if (PLANES == 2)
            acc[mi][ni] = __builtin_amdgcn_mfma_f32_16x16x32_bf16(af[1][mi], bfr[ni], acc[mi][ni], 0, 0, 0);
        }
    }
  }

  #pragma unroll
  for (int mi = 0; mi < 4; mi++)
    #pragma unroll
    for (int ni = 0; ni < 4; ni++) {
      const int col = bn * 128 + wn * 64 + ni * 16 + l15;
      const float bv = BIAS ? bias[col] : 0.f;
      #pragma unroll
      for (int reg = 0; reg < 4; reg++) {
        const int row = bm * 128 + wm * 64 + mi * 16 + l4 * 4 + reg;
        const float val = acc[mi][ni][reg] + bv;
        if constexpr (sizeof(OUT_T) == 2) C[(size_t)row * N + col] = (OUT_T)f2bf(val);
        else                              C[(size_t)row * N + col] = val;
      }
    }
}

// Fused grouped conv3x3 (groups=64, 4in/4out) + bias + 2x2 maxpool.
// qkv bf16 (b,tok,2304) at t*768+chan0; out f32 (b*3+t, y, x, 256).
__global__ __launch_bounds__(256)
void conv_pool(const u16* __restrict__ qkv, const float* __restrict__ wsrc,
               const float* __restrict__ bias, float* __restrict__ gout,
               int chan0, int Pout, int st, int pd, int dl)
{
  __shared__ float wl[64 * 145];
  const int g = threadIdx.x;
  const int ty = threadIdx.y;
  const int tid = ty * 64 + g;
  for (int i = tid; i < 9216; i += 256) {
    const int oc = i / 36, rem = i - oc * 36;
    wl[(oc >> 2) * 145 + (oc & 3) * 36 + rem] = wsrc[i];
  }
  __syncthreads();

  const int bt = blockIdx.x;
  const int b = bt / 3, t = bt - b * 3;
  const int total = Pout * Pout;
  const int p = blockIdx.y * 4 + ty;
  if (p >= total) return;
  const int y = p / Pout, x = p - y * Pout;

  const f32x4 bias4 = *(const f32x4*)&bias[g * 4];
  f32x4 best;
  #pragma unroll
  for (int j = 0; j < 4; j++) best[j] = -3.4e38f;
  const float* wg = &wl[g * 145];

  #pragma unroll
  for (int dy = 0; dy < 2; dy++)
    #pragma unroll
    for (int dx = 0; dx < 2; dx++) {
      const int py = 2 * y + dy, px = 2 * x + dx;
      f32x4 c4 = bias4;
      #pragma unroll
      for (int ky = 0; ky < 3; ky++) {
        const int iy = py * st - pd + ky * dl;
        if (iy < 0 || iy >= 56) continue;
        #pragma unroll
        for (int kx = 0; kx < 3; kx++) {
          const int ix = px * st - pd + kx * dl;
          if (ix < 0 || ix >= 56) continue;
          const u16x4 in4 = *(const u16x4*)&qkv[(size_t)(b * 3136 + iy * 56 + ix) * 2304 + t * 768 + chan0 + g * 4];
          const float f0 = bf2f(in4[0]), f1 = bf2f(in4[1]), f2 = bf2f(in4[2]), f3 = bf2f(in4[3]);
          #pragma unroll
          for (int oc = 0; oc < 4; oc++) {
            const float* wp = &wg[oc * 36 + ky * 3 + kx];
            c4[oc] += f0 * wp[0] + f1 * wp[9] + f2 * wp[18] + f3 * wp[27];
          }
        }
      }
      #pragma unroll
      for (int j = 0; j < 4; j++) best[j] = fmaxf(best[j], c4[j]);
    }
  *(f32x4*)&gout[((size_t)bt * total + p) * 256 + g * 4] = best;
}

// Windowed attention; SRC=0 reads bf16 qkv, SRC=1 reads f32 conv outputs.
// Writes fused as bf16 hi+lo split planes.
template<int SRC>
__global__ __launch_bounds__(256)
void attn_win(const void* __restrict__ src, u16* __restrict__ fh, u16* __restrict__ fl,
              int side, int Hs, int head_base0, int rep)
{
  __shared__ float Qs[49][65], Ks[49][65], Vs[49][65], Ss[49][50];
  const int tid = threadIdx.x;
  const int nreg = side * side;
  int bid = blockIdx.x;
  const int h = bid & 3; bid >>= 2;
  const int r = bid % nreg;
  const int b = bid / nreg;
  const int hr = r / side, wr = r - hr * side;

  for (int v = tid; v < 49 * 16; v += 256) {
    const int pp = v >> 4, d0 = (v & 15) * 4;
    const int py = pp / 7, pxx = pp - py * 7;
    const int yy = hr * 7 + py, xx = wr * 7 + pxx;
    #pragma unroll
    for (int t = 0; t < 3; t++) {
      float f0, f1, f2, f3;
      if (SRC == 0) {
        const u16* sb = (const u16*)src;
        const u16x4 val = *(const u16x4*)&sb[(size_t)(b * 3136 + yy * 56 + xx) * 2304 + t * 768 + h * 64 + d0];
        f0 = bf2f(val[0]); f1 = bf2f(val[1]); f2 = bf2f(val[2]); f3 = bf2f(val[3]);
      } else {
        const float* sf = (const float*)src;
        const f32x4 val = *(const f32x4*)&sf[((size_t)(b * 3 + t) * (Hs * Hs) + yy * Hs + xx) * 256 + h * 64 + d0];
        f0 = val[0]; f1 = val[1]; f2 = val[2]; f3 = val[3];
      }
      float* dst = (t == 0) ? &Qs[pp][d0] : (t == 1) ? &Ks[pp][d0] : &Vs[pp][d0];
      dst[0] = f0; dst[1] = f1; dst[2] = f2; dst[3] = f3;
    }
  }
  __syncthreads();

  for (int e = tid; e < 49 * 49; e += 256) {
    const int pp = e / 49, qq = e - pp * 49;
    float acc = 0.f;
    #pragma unroll 8
    for (int d = 0; d < 64; d++) acc += Qs[pp][d] * Ks[qq][d];
    Ss[pp][qq] = acc * 0.125f;
  }
  __syncthreads();

  if (tid < 49) {
    float mx = -3.4e38f;
    for (int qq = 0; qq < 49; qq++) mx = fmaxf(mx, Ss[tid][qq]);
    float sum = 0.f;
    for (int qq = 0; qq < 49; qq++) { const float ev = expf(Ss[tid][qq] - mx); Ss[tid][qq] = ev; sum += ev; }
    const float inv = 1.f / sum;
    for (int qq = 0; qq < 49; qq++) Ss[tid][qq] *= inv;
  }
  __syncthreads();

  const int head = head_base0 + h;
  for (int e = tid; e < 49 * 64; e += 256) {
    const int pp = e >> 6, d = e & 63;
    float acc = 0.f;
    #pragma unroll 7
    for (int qq = 0; qq < 49; qq++) acc += Ss[pp][qq] * Vs[qq][d];
    const u16 hi = f2bf(acc);
    const u16 lo = f2bf(acc - bf2f(hi));
    for (int m = 0; m < rep; m++) {
      const int n = (m * nreg + r) * 49 + pp;
      const size_t o = ((size_t)b * 3136 + n) * 768 + head * 64 + d;
      fh[o] = hi; fl[o] = lo;
    }
  }
}

extern "C" void kernel_launch(void* const* d_in, const int* in_sizes, int n_in,
                              void* d_out, int out_size, void* d_ws, size_t ws_size,
                              hipStream_t stream)
{
  const float* x      = (const float*)d_in[0];
  const float* w_qkv  = (const float*)d_in[1];
  const float* w_proj = (const float*)d_in[2];
  const float* b_proj = (const float*)d_in[3];
  const float* c1w    = (const float*)d_in[4];
  const float* c1b    = (const float*)d_in[5];
  const float* c2w    = (const float*)d_in[6];
  const float* c2b    = (const float*)d_in[7];
  float* out = (float*)d_out;

  u16 *xh, *wqkvh, *wprojh, *qkvb, *fh, *fl;
  float *g1, *g2;
  hipGetSymbolAddress((void**)&xh,     HIP_SYMBOL(g_xh));
  hipGetSymbolAddress((void**)&wqkvh,  HIP_SYMBOL(g_wqkvh));
  hipGetSymbolAddress((void**)&wprojh, HIP_SYMBOL(g_wprojh));
  hipGetSymbolAddress((void**)&qkvb,   HIP_SYMBOL(g_qkv));
  hipGetSymbolAddress((void**)&g1,     HIP_SYMBOL(g_g1));
  hipGetSymbolAddress((void**)&g2,     HIP_SYMBOL(g_g2));
  hipGetSymbolAddress((void**)&fh,     HIP_SYMBOL(g_fh));
  hipGetSymbolAddress((void**)&fl,     HIP_SYMBOL(g_fl));

  // 0) one-shot bf16 conversions
  cvt_bf16<<<2048, 256, 0, stream>>>(x,      xh,     50176 * 768 / 4);
  cvt_bf16<<<512,  256, 0, stream>>>(w_qkv,  wqkvh,  2304 * 768 / 4);
  cvt_bf16<<<512,  256, 0, stream>>>(w_proj, wprojh, 768 * 768 / 4);

  // 1) QKV GEMM (pure bf16, 1 MFMA): (50176,768)@(2304,768)^T -> qkv bf16
  gemm_lds<1, false, u16><<<dim3(2304 / 128, 50176 / 128), 256, 0, stream>>>(
      xh, nullptr, wqkvh, nullptr, qkvb, 2304, 768);

  // 2) convs for scales 1 and 2
  conv_pool<<<dim3(48, 196), dim3(64, 4), 0, stream>>>(qkvb, c1w, c1b, g1, 256, 28, 1, 1, 1);
  conv_pool<<<dim3(48, 49),  dim3(64, 4), 0, stream>>>(qkvb, c2w, c2b, g2, 512, 14, 2, 2, 2);

  // 3) windowed attention per scale -> fused (hi/lo bf16 split)
  attn_win<0><<<16 * 64 * 4, 256, 0, stream>>>(qkvb, fh, fl, 8, 56, 0, 1);
  attn_win<1><<<16 * 16 * 4, 256, 0, stream>>>(g1,   fh, fl, 4, 28, 4, 4);
  attn_win<1><<<16 * 4 * 4,  256, 0, stream>>>(g2,   fh, fl, 2, 14, 8, 16);

  // 4) proj GEMM (A-split 2 MFMA) + bias -> out (f32)
  gemm_lds<2, true, float><<<dim3(768 / 128, 50176 / 128), 256, 0, stream>>>(
      fh, fl, wprojh, b_proj, out, 768, 768);
}

// Round 4
// 897.188 us; speedup vs baseline: 1.7410x; 1.1678x over previous
//
#include <hip/hip_runtime.h>

typedef __attribute__((ext_vector_type(4))) float f32x4;
typedef __attribute__((ext_vector_type(8))) short bf16x8;
typedef __attribute__((ext_vector_type(4))) unsigned short u16x4;
typedef unsigned short u16;

// Static device intermediates (BSS; fully rewritten every launch).
__device__ static u16   g_xh[(size_t)50176 * 768];     // bf16(x)            77 MB
__device__ static u16   g_wqkvh[(size_t)2304 * 768];   // bf16(w_qkv)       3.5 MB
__device__ static u16   g_wprojh[(size_t)768 * 768];   // bf16(w_proj)      1.2 MB
__device__ static u16   g_qkv[(size_t)50176 * 2304];   // qkv bf16          231 MB
__device__ static u16   g_g1[(size_t)48 * 784 * 256];  // conv1 out bf16     19 MB
__device__ static u16   g_g2[(size_t)48 * 196 * 256];  // conv2 out bf16    4.8 MB
__device__ static u16   g_fh[(size_t)50176 * 768];     // fused hi bf16      77 MB
__device__ static u16   g_fl[(size_t)50176 * 768];     // fused lo bf16      77 MB

static __device__ __forceinline__ u16 f2bf(float x){
  unsigned u = __float_as_uint(x);
  u += 0x7fffu + ((u >> 16) & 1u);
  return (u16)(u >> 16);
}
static __device__ __forceinline__ float bf2f(u16 h){
  return __uint_as_float(((unsigned)h) << 16);
}

// f32 -> bf16 (RNE), vectorized x4, grid-stride.
__global__ __launch_bounds__(256)
void cvt_bf16(const float* __restrict__ in, u16* __restrict__ out, int n4)
{
  int i = blockIdx.x * blockDim.x + threadIdx.x;
  const int stride = gridDim.x * blockDim.x;
  for (; i < n4; i += stride) {
    const f32x4 v = ((const f32x4*)in)[i];
    u16x4 o;
    #pragma unroll
    for (int j = 0; j < 4; j++) o[j] = f2bf(v[j]);
    ((u16x4*)out)[i] = o;
  }
}

// C[m][n] = sum_k (A0[m][k] (+A1[m][k])) * B[n][k] (+ bias[n])
// 128x128 tile, BK=64, global_load_lds w16 staging, XOR-swizzled LDS.
template<int PLANES, bool BIAS, typename OUT_T>
__global__ __launch_bounds__(256)
void gemm_lds(const u16* __restrict__ A0, const u16* __restrict__ A1,
              const u16* __restrict__ Bw, const float* __restrict__ bias,
              OUT_T* __restrict__ C, int N, int K)
{
  __shared__ __align__(16) u16 lds[(PLANES + 1) * 8192];
  char* ldsb = (char*)lds;
  const int tid = threadIdx.x;
  const int lane = tid & 63;
  const int w = tid >> 6;
  const int wm = w >> 1, wn = w & 1;
  const int bm = blockIdx.y, bn = blockIdx.x;
  const int l15 = lane & 15, l4 = lane >> 4;
  const int lr = lane >> 3;
  const int cxor = (lane & 7) ^ lr;

  f32x4 acc[4][4];
  #pragma unroll
  for (int i = 0; i < 4; i++)
    #pragma unroll
    for (int j = 0; j < 4; j++) acc[i][j] = (f32x4)0.f;

  const u16* aptr[2] = {A0, A1};
  const int num_chunks = (PLANES + 1) * 16;

  for (int kt = 0; kt < K; kt += 64) {
    __syncthreads();
    for (int q = w; q < num_chunks; q += 4) {
      const int plane = q >> 4, i = q & 15;
      const int row = i * 8 + lr;
      const u16* src;
      if (plane < PLANES) src = aptr[plane] + (size_t)(bm * 128 + row) * K + kt + cxor * 8;
      else                src = Bw          + (size_t)(bn * 128 + row) * K + kt + cxor * 8;
      __builtin_amdgcn_global_load_lds(
          (__attribute__((address_space(1))) const void*)src,
          (__attribute__((address_space(3))) void*)(ldsb + q * 1024),
          16, 0, 0);
    }
    __syncthreads();

    #pragma unroll
    for (int ks = 0; ks < 2; ks++) {
      bf16x8 af[PLANES][4], bfr[4];
      #pragma unroll
      for (int mi = 0; mi < 4; mi++) {
        const int row = wm * 64 + mi * 16 + l15;
        const int bo = row * 128 + (((l4 + 4 * ks) ^ (row & 7)) << 4);
        #pragma unroll
        for (int p = 0; p < PLANES; p++)
          af[p][mi] = *(const bf16x8*)(ldsb + p * 16384 + bo);
      }
      #pragma unroll
      for (int ni = 0; ni < 4; ni++) {
        const int row = wn * 64 + ni * 16 + l15;
        const int bo = row * 128 + (((l4 + 4 * ks) ^ (row & 7)) << 4);
        bfr[ni] = *(const bf16x8*)(ldsb + PLANES * 16384 + bo);
      }
      #pragma unroll
      for (int mi = 0; mi < 4; mi++)
        #pragma unroll
        for (int ni = 0; ni < 4; ni++) {
          acc[mi][ni] = __builtin_amdgcn_mfma_f32_16x16x32_bf16(af[0][mi], bfr[ni], acc[mi][ni], 0, 0, 0);
          if (PLANES == 2)
            acc[mi][ni] = __builtin_amdgcn_mfma_f32_16x16x32_bf16(af[1][mi], bfr[ni], acc[mi][ni], 0, 0, 0);
        }
    }
  }

  #pragma unroll
  for (int mi = 0; mi < 4; mi++)
    #pragma unroll
    for (int ni = 0; ni < 4; ni++) {
      const int col = bn * 128 + wn * 64 + ni * 16 + l15;
      const float bv = BIAS ? bias[col] : 0.f;
      #pragma unroll
      for (int reg = 0; reg < 4; reg++) {
        const int row = bm * 128 + wm * 64 + mi * 16 + l4 * 4 + reg;
        const float val = acc[mi][ni][reg] + bv;
        if constexpr (sizeof(OUT_T) == 2) C[(size_t)row * N + col] = (OUT_T)f2bf(val);
        else                              C[(size_t)row * N + col] = val;
      }
    }
}

// Fused grouped conv3x3 (groups=64, 4in/4out) + bias + 2x2 maxpool -> bf16.
__global__ __launch_bounds__(256)
void conv_pool(const u16* __restrict__ qkv, const float* __restrict__ wsrc,
               const float* __restrict__ bias, u16* __restrict__ gout,
               int chan0, int Pout, int st, int pd, int dl)
{
  __shared__ float wl[64 * 145];
  const int g = threadIdx.x;
  const int ty = threadIdx.y;
  const int tid = ty * 64 + g;
  for (int i = tid; i < 9216; i += 256) {
    const int oc = i / 36, rem = i - oc * 36;
    wl[(oc >> 2) * 145 + (oc & 3) * 36 + rem] = wsrc[i];
  }
  __syncthreads();

  const int bt = blockIdx.x;
  const int b = bt / 3, t = bt - b * 3;
  const int total = Pout * Pout;
  const int p = blockIdx.y * 4 + ty;
  if (p >= total) return;
  const int y = p / Pout, x = p - y * Pout;

  const f32x4 bias4 = *(const f32x4*)&bias[g * 4];
  f32x4 best;
  #pragma unroll
  for (int j = 0; j < 4; j++) best[j] = -3.4e38f;
  const float* wg = &wl[g * 145];

  #pragma unroll
  for (int dy = 0; dy < 2; dy++)
    #pragma unroll
    for (int dx = 0; dx < 2; dx++) {
      const int py = 2 * y + dy, px = 2 * x + dx;
      f32x4 c4 = bias4;
      #pragma unroll
      for (int ky = 0; ky < 3; ky++) {
        const int iy = py * st - pd + ky * dl;
        if (iy < 0 || iy >= 56) continue;
        #pragma unroll
        for (int kx = 0; kx < 3; kx++) {
          const int ix = px * st - pd + kx * dl;
          if (ix < 0 || ix >= 56) continue;
          const u16x4 in4 = *(const u16x4*)&qkv[(size_t)(b * 3136 + iy * 56 + ix) * 2304 + t * 768 + chan0 + g * 4];
          const float f0 = bf2f(in4[0]), f1 = bf2f(in4[1]), f2 = bf2f(in4[2]), f3 = bf2f(in4[3]);
          #pragma unroll
          for (int oc = 0; oc < 4; oc++) {
            const float* wp = &wg[oc * 36 + ky * 3 + kx];
            c4[oc] += f0 * wp[0] + f1 * wp[9] + f2 * wp[18] + f3 * wp[27];
          }
        }
      }
      #pragma unroll
      for (int j = 0; j < 4; j++) best[j] = fmaxf(best[j], c4[j]);
    }
  u16x4 o4;
  #pragma unroll
  for (int j = 0; j < 4; j++) o4[j] = f2bf(best[j]);
  *(u16x4*)&gout[((size_t)bt * total + p) * 256 + g * 4] = o4;
}

// MFMA windowed attention: one WAVE per (b, region, head); 4 waves/block.
// Positions padded 49->64 (rows clamped to 48 = duplicates; cols masked).
// SRC=0: qkv bf16 (tok,2304) planes t*768; SRC=1: g bf16 ((b*3+t),pix,256).
template<int SRC>
__global__ __launch_bounds__(256)
void attn_mfma(const u16* __restrict__ src, u16* __restrict__ fh, u16* __restrict__ fl,
               int side, int Hs, int head_base, int rep)
{
  __shared__ __align__(16) u16 sV[4][64 * 64];
  __shared__ __align__(16) u16 sP[4][64 * 64];
  const int tid = threadIdx.x;
  const int lane = tid & 63;
  const int w = tid >> 6;
  const int nreg = side * side;
  int unit = blockIdx.x * 4 + w;
  const int h = unit & 3; unit >>= 2;
  const int r = unit % nreg;
  const int b = unit / nreg;
  const int hr = r / side, wr = r - hr * side;
  const int l15 = lane & 15, l4 = lane >> 4;

  char* vb = (char*)sV[w];
  char* pb = (char*)sP[w];

  auto gidx = [&](int t, int pp, int c) -> size_t {
    const int py = pp / 7, px = pp - py * 7;
    const int yy = hr * 7 + py, xx = wr * 7 + px;
    if (SRC == 0) return ((size_t)(b * 3136 + yy * 56 + xx)) * 2304 + (size_t)(t * 768 + h * 64 + c);
    else          return ((size_t)(b * 3 + t)) * ((size_t)Hs * Hs * 256) + (size_t)(yy * Hs + xx) * 256 + h * 64 + c;
  };

  // ---- stage V (t=2), rows clamped; swizzle byte ^= ((q>>3)&3)<<5 ----
  for (int i = lane; i < 1024; i += 64) {
    const int q = i >> 4, dc = i & 15;
    const int qs = q > 48 ? 48 : q;
    const u16x4 v4 = *(const u16x4*)&src[gidx(2, qs, dc * 4)];
    *(u16x4*)(vb + ((q * 128 + dc * 8) ^ (((q >> 3) & 3) << 5))) = v4;
  }

  // ---- QK^T: S = Q*K^T, frags straight from global ----
  f32x4 s[4][4];
  #pragma unroll
  for (int i = 0; i < 4; i++)
    #pragma unroll
    for (int j = 0; j < 4; j++) s[i][j] = (f32x4)0.f;

  bf16x8 bk[4][2];
  #pragma unroll
  for (int ni = 0; ni < 4; ni++) {
    const int q = ni * 16 + l15;
    const int qs = q > 48 ? 48 : q;
    #pragma unroll
    for (int ks = 0; ks < 2; ks++)
      bk[ni][ks] = *(const bf16x8*)&src[gidx(1, qs, ks * 32 + l4 * 8)];
  }
  #pragma unroll
  for (int mi = 0; mi < 4; mi++) {
    const int p = mi * 16 + l15;
    const int ps = p > 48 ? 48 : p;
    const bf16x8 a0 = *(const bf16x8*)&src[gidx(0, ps, l4 * 8)];
    const bf16x8 a1 = *(const bf16x8*)&src[gidx(0, ps, 32 + l4 * 8)];
    #pragma unroll
    for (int ni = 0; ni < 4; ni++) {
      s[mi][ni] = __builtin_amdgcn_mfma_f32_16x16x32_bf16(a0, bk[ni][0], s[mi][ni], 0, 0, 0);
      s[mi][ni] = __builtin_amdgcn_mfma_f32_16x16x32_bf16(a1, bk[ni][1], s[mi][ni], 0, 0, 0);
    }
  }

  // ---- mask cols q>=49, in-register softmax (unnormalized P; O scaled later)
  #pragma unroll
  for (int ni = 0; ni < 4; ni++) {
    const bool bad = (ni * 16 + l15) > 48;
    #pragma unroll
    for (int mi = 0; mi < 4; mi++)
      #pragma unroll
      for (int reg = 0; reg < 4; reg++)
        s[mi][ni][reg] = bad ? -1e30f : s[mi][ni][reg];
  }

  float inv[4][4];
  #pragma unroll
  for (int mi = 0; mi < 4; mi++)
    #pragma unroll
    for (int reg = 0; reg < 4; reg++) {
      float m = fmaxf(fmaxf(s[mi][0][reg], s[mi][1][reg]), fmaxf(s[mi][2][reg], s[mi][3][reg]));
      m = fmaxf(m, __shfl_xor(m, 1));
      m = fmaxf(m, __shfl_xor(m, 2));
      m = fmaxf(m, __shfl_xor(m, 4));
      m = fmaxf(m, __shfl_xor(m, 8));
      float partial = 0.f;
      #pragma unroll
      for (int ni = 0; ni < 4; ni++) {
        const float e = __expf((s[mi][ni][reg] - m) * 0.125f);
        s[mi][ni][reg] = e;
        partial += e;
      }
      partial += __shfl_xor(partial, 1);
      partial += __shfl_xor(partial, 2);
      partial += __shfl_xor(partial, 4);
      partial += __shfl_xor(partial, 8);
      inv[mi][reg] = 1.f / partial;
    }

  // ---- P -> LDS (bf16, XOR-swizzled rows) ----
  #pragma unroll
  for (int mi = 0; mi < 4; mi++)
    #pragma unroll
    for (int ni = 0; ni < 4; ni++)
      #pragma unroll
      for (int reg = 0; reg < 4; reg++) {
        const int row = mi * 16 + l4 * 4 + reg;
        const int col = ni * 16 + l15;
        *(u16*)(pb + ((row * 128 + col * 2) ^ ((row & 7) << 4))) = f2bf(s[mi][ni][reg]);
      }
  __syncthreads();

  // ---- PV: O = P*V ----
  f32x4 o[4][4];
  #pragma unroll
  for (int i = 0; i < 4; i++)
    #pragma unroll
    for (int j = 0; j < 4; j++) o[i][j] = (f32x4)0.f;

  #pragma unroll
  for (int ks = 0; ks < 2; ks++) {
    bf16x8 bv[4];
    #pragma unroll
    for (int ni = 0; ni < 4; ni++)
      #pragma unroll
      for (int j = 0; j < 8; j++) {
        const int q = ks * 32 + l4 * 8 + j;
        bv[ni][j] = *(const short*)(vb + ((q * 128 + (ni * 16 + l15) * 2) ^ (((q >> 3) & 3) << 5)));
      }
    #pragma unroll
    for (int mi = 0; mi < 4; mi++) {
      const int row = mi * 16 + l15;
      const bf16x8 pa = *(const bf16x8*)(pb + ((row * 128 + (ks * 4 + l4) * 16) ^ ((row & 7) << 4)));
      #pragma unroll
      for (int ni = 0; ni < 4; ni++)
        o[mi][ni] = __builtin_amdgcn_mfma_f32_16x16x32_bf16(pa, bv[ni], o[mi][ni], 0, 0, 0);
    }
  }

  // ---- epilogue: scale by 1/sum, hi/lo bf16, replicate ----
  const int head = head_base + h;
  #pragma unroll
  for (int mi = 0; mi < 4; mi++)
    #pragma unroll
    for (int reg = 0; reg < 4; reg++) {
      const int p = mi * 16 + l4 * 4 + reg;
      if (p >= 49) continue;
      const float iv = inv[mi][reg];
      u16 hv[4], lv[4];
      #pragma unroll
      for (int ni = 0; ni < 4; ni++) {
        const float val = o[mi][ni][reg] * iv;
        hv[ni] = f2bf(val);
        lv[ni] = f2bf(val - bf2f(hv[ni]));
      }
      for (int m = 0; m < rep; m++) {
        const size_t ob = ((size_t)b * 3136 + (size_t)(m * nreg + r) * 49 + p) * 768 + head * 64 + l15;
        #pragma unroll
        for (int ni = 0; ni < 4; ni++) { fh[ob + ni * 16] = hv[ni]; fl[ob + ni * 16] = lv[ni]; }
      }
    }
}

extern "C" void kernel_launch(void* const* d_in, const int* in_sizes, int n_in,
                              void* d_out, int out_size, void* d_ws, size_t ws_size,
                              hipStream_t stream)
{
  const float* x      = (const float*)d_in[0];
  const float* w_qkv  = (const float*)d_in[1];
  const float* w_proj = (const float*)d_in[2];
  const float* b_proj = (const float*)d_in[3];
  const float* c1w    = (const float*)d_in[4];
  const float* c1b    = (const float*)d_in[5];
  const float* c2w    = (const float*)d_in[6];
  const float* c2b    = (const float*)d_in[7];
  float* out = (float*)d_out;

  u16 *xh, *wqkvh, *wprojh, *qkvb, *g1, *g2, *fh, *fl;
  hipGetSymbolAddress((void**)&xh,     HIP_SYMBOL(g_xh));
  hipGetSymbolAddress((void**)&wqkvh,  HIP_SYMBOL(g_wqkvh));
  hipGetSymbolAddress((void**)&wprojh, HIP_SYMBOL(g_wprojh));
  hipGetSymbolAddress((void**)&qkvb,   HIP_SYMBOL(g_qkv));
  hipGetSymbolAddress((void**)&g1,     HIP_SYMBOL(g_g1));
  hipGetSymbolAddress((void**)&g2,     HIP_SYMBOL(g_g2));
  hipGetSymbolAddress((void**)&fh,     HIP_SYMBOL(g_fh));
  hipGetSymbolAddress((void**)&fl,     HIP_SYMBOL(g_fl));

  // 0) one-shot bf16 conversions
  cvt_bf16<<<2048, 256, 0, stream>>>(x,      xh,     50176 * 768 / 4);
  cvt_bf16<<<512,  256, 0, stream>>>(w_qkv,  wqkvh,  2304 * 768 / 4);
  cvt_bf16<<<512,  256, 0, stream>>>(w_proj, wprojh, 768 * 768 / 4);

  // 1) QKV GEMM (bf16): (50176,768)@(2304,768)^T -> qkv bf16
  gemm_lds<1, false, u16><<<dim3(2304 / 128, 50176 / 128), 256, 0, stream>>>(
      xh, nullptr, wqkvh, nullptr, qkvb, 2304, 768);

  // 2) convs for scales 1 and 2 (bf16 out)
  conv_pool<<<dim3(48, 196), dim3(64, 4), 0, stream>>>(qkvb, c1w, c1b, g1, 256, 28, 1, 1, 1);
  conv_pool<<<dim3(48, 49),  dim3(64, 4), 0, stream>>>(qkvb, c2w, c2b, g2, 512, 14, 2, 2, 2);

  // 3) MFMA windowed attention per scale -> fused (hi/lo bf16)
  attn_mfma<0><<<16 * 64 * 4 / 4, 256, 0, stream>>>(qkvb, fh, fl, 8, 56, 0, 1);
  attn_mfma<1><<<16 * 16 * 4 / 4, 256, 0, stream>>>(g1,   fh, fl, 4, 28, 4, 4);
  attn_mfma<1><<<16 * 4 * 4 / 4,  256, 0, stream>>>(g2,   fh, fl, 2, 14, 8, 16);

  // 4) proj GEMM (A-split 2 MFMA) + bias -> out (f32)
  gemm_lds<2, true, float><<<dim3(768 / 128, 50176 / 128), 256, 0, stream>>>(
      fh, fl, wprojh, b_proj, out, 768, 768);
}

// Round 5
// 705.286 us; speedup vs baseline: 2.2147x; 1.2721x over previous
//
#include <hip/hip_runtime.h>

typedef __attribute__((ext_vector_type(4))) float f32x4;
typedef __attribute__((ext_vector_type(8))) short bf16x8;
typedef __attribute__((ext_vector_type(4))) unsigned short u16x4;
typedef unsigned short u16;

// Static device intermediates (BSS; fully rewritten every launch).
__device__ static u16   g_xh[(size_t)50176 * 768];     // bf16(x)            77 MB
__device__ static u16   g_wqkvh[(size_t)2304 * 768];   // bf16(w_qkv)       3.5 MB
__device__ static u16   g_wprojh[(size_t)768 * 768];   // bf16(w_proj)      1.2 MB
__device__ static u16   g_qkv[(size_t)50176 * 2304];   // qkv bf16          231 MB
__device__ static u16   g_g1[(size_t)48 * 784 * 256];  // conv1 out bf16     19 MB
__device__ static u16   g_g2[(size_t)48 * 196 * 256];  // conv2 out bf16    4.8 MB
__device__ static u16   g_fh[(size_t)50176 * 768];     // fused bf16         77 MB

static __device__ __forceinline__ u16 f2bf(float x){
  unsigned u = __float_as_uint(x);
  u += 0x7fffu + ((u >> 16) & 1u);
  return (u16)(u >> 16);
}
static __device__ __forceinline__ float bf2f(u16 h){
  return __uint_as_float(((unsigned)h) << 16);
}

// f32 -> bf16 (RNE), vectorized x4, grid-stride.
__global__ __launch_bounds__(256)
void cvt_bf16(const float* __restrict__ in, u16* __restrict__ out, int n4)
{
  int i = blockIdx.x * blockDim.x + threadIdx.x;
  const int stride = gridDim.x * blockDim.x;
  for (; i < n4; i += stride) {
    const f32x4 v = ((const f32x4*)in)[i];
    u16x4 o;
    #pragma unroll
    for (int j = 0; j < 4; j++) o[j] = f2bf(v[j]);
    ((u16x4*)out)[i] = o;
  }
}

// C[m][n] = sum_k A[m][k] * B[n][k] (+ bias[n]); bf16, 128x128 tile, BK=64,
// global_load_lds w16 staging, XOR-swizzled LDS, bijective XCD block swizzle
// (1D grid, bn-fastest within an XCD chunk -> A panel stays in that XCD's L2).
template<bool BIAS, typename OUT_T>
__global__ __launch_bounds__(256)
void gemm_lds(const u16* __restrict__ A0, const u16* __restrict__ Bw,
              const float* __restrict__ bias, OUT_T* __restrict__ C,
              int N, int K, int GX)
{
  __shared__ __align__(16) u16 lds[2 * 8192];
  char* ldsb = (char*)lds;
  const int tid = threadIdx.x;
  const int lane = tid & 63;
  const int w = tid >> 6;
  const int wm = w >> 1, wn = w & 1;

  // T1 bijective XCD swizzle (m204): same-XCD consecutive ids sweep bn.
  const int nwg = gridDim.x;
  const int bid = blockIdx.x;
  const int q8 = nwg >> 3, r8 = nwg & 7;
  const int xcd = bid & 7, lid = bid >> 3;
  const int swz = (xcd < r8 ? xcd * (q8 + 1) : r8 * (q8 + 1) + (xcd - r8) * q8) + lid;
  const int bn = swz % GX;
  const int bm = swz / GX;

  const int l15 = lane & 15, l4 = lane >> 4;
  const int lr = lane >> 3;
  const int cxor = (lane & 7) ^ lr;

  f32x4 acc[4][4];
  #pragma unroll
  for (int i = 0; i < 4; i++)
    #pragma unroll
    for (int j = 0; j < 4; j++) acc[i][j] = (f32x4)0.f;

  for (int kt = 0; kt < K; kt += 64) {
    __syncthreads();
    for (int q = w; q < 32; q += 4) {
      const int plane = q >> 4, i = q & 15;
      const int row = i * 8 + lr;
      const u16* src;
      if (plane == 0) src = A0 + (size_t)(bm * 128 + row) * K + kt + cxor * 8;
      else            src = Bw + (size_t)(bn * 128 + row) * K + kt + cxor * 8;
      __builtin_amdgcn_global_load_lds(
          (__attribute__((address_space(1))) const void*)src,
          (__attribute__((address_space(3))) void*)(ldsb + q * 1024),
          16, 0, 0);
    }
    __syncthreads();

    #pragma unroll
    for (int ks = 0; ks < 2; ks++) {
      bf16x8 af[4], bfr[4];
      #pragma unroll
      for (int mi = 0; mi < 4; mi++) {
        const int row = wm * 64 + mi * 16 + l15;
        const int bo = row * 128 + (((l4 + 4 * ks) ^ (row & 7)) << 4);
        af[mi] = *(const bf16x8*)(ldsb + bo);
      }
      #pragma unroll
      for (int ni = 0; ni < 4; ni++) {
        const int row = wn * 64 + ni * 16 + l15;
        const int bo = row * 128 + (((l4 + 4 * ks) ^ (row & 7)) << 4);
        bfr[ni] = *(const bf16x8*)(ldsb + 16384 + bo);
      }
      #pragma unroll
      for (int mi = 0; mi < 4; mi++)
        #pragma unroll
        for (int ni = 0; ni < 4; ni++)
          acc[mi][ni] = __builtin_amdgcn_mfma_f32_16x16x32_bf16(af[mi], bfr[ni], acc[mi][ni], 0, 0, 0);
    }
  }

  #pragma unroll
  for (int mi = 0; mi < 4; mi++)
    #pragma unroll
    for (int ni = 0; ni < 4; ni++) {
      const int col = bn * 128 + wn * 64 + ni * 16 + l15;
      const float bv = BIAS ? bias[col] : 0.f;
      #pragma unroll
      for (int reg = 0; reg < 4; reg++) {
        const int row = bm * 128 + wm * 64 + mi * 16 + l4 * 4 + reg;
        const float val = acc[mi][ni][reg] + bv;
        if constexpr (sizeof(OUT_T) == 2) C[(size_t)row * N + col] = (OUT_T)f2bf(val);
        else                              C[(size_t)row * N + col] = val;
      }
    }
}

// Fused grouped conv3x3 (groups=64, 4in/4out) + bias + 2x2 maxpool -> bf16.
__global__ __launch_bounds__(256)
void conv_pool(const u16* __restrict__ qkv, const float* __restrict__ wsrc,
               const float* __restrict__ bias, u16* __restrict__ gout,
               int chan0, int Pout, int st, int pd, int dl)
{
  __shared__ float wl[64 * 145];
  const int g = threadIdx.x;
  const int ty = threadIdx.y;
  const int tid = ty * 64 + g;
  for (int i = tid; i < 9216; i += 256) {
    const int oc = i / 36, rem = i - oc * 36;
    wl[(oc >> 2) * 145 + (oc & 3) * 36 + rem] = wsrc[i];
  }
  __syncthreads();

  const int bt = blockIdx.x;
  const int b = bt / 3, t = bt - b * 3;
  const int total = Pout * Pout;
  const int p = blockIdx.y * 4 + ty;
  if (p >= total) return;
  const int y = p / Pout, x = p - y * Pout;

  const f32x4 bias4 = *(const f32x4*)&bias[g * 4];
  f32x4 best;
  #pragma unroll
  for (int j = 0; j < 4; j++) best[j] = -3.4e38f;
  const float* wg = &wl[g * 145];

  #pragma unroll
  for (int dy = 0; dy < 2; dy++)
    #pragma unroll
    for (int dx = 0; dx < 2; dx++) {
      const int py = 2 * y + dy, px = 2 * x + dx;
      f32x4 c4 = bias4;
      #pragma unroll
      for (int ky = 0; ky < 3; ky++) {
        const int iy = py * st - pd + ky * dl;
        if (iy < 0 || iy >= 56) continue;
        #pragma unroll
        for (int kx = 0; kx < 3; kx++) {
          const int ix = px * st - pd + kx * dl;
          if (ix < 0 || ix >= 56) continue;
          const u16x4 in4 = *(const u16x4*)&qkv[(size_t)(b * 3136 + iy * 56 + ix) * 2304 + t * 768 + chan0 + g * 4];
          const float f0 = bf2f(in4[0]), f1 = bf2f(in4[1]), f2 = bf2f(in4[2]), f3 = bf2f(in4[3]);
          #pragma unroll
          for (int oc = 0; oc < 4; oc++) {
            const float* wp = &wg[oc * 36 + ky * 3 + kx];
            c4[oc] += f0 * wp[0] + f1 * wp[9] + f2 * wp[18] + f3 * wp[27];
          }
        }
      }
      #pragma unroll
      for (int j = 0; j < 4; j++) best[j] = fmaxf(best[j], c4[j]);
    }
  u16x4 o4;
  #pragma unroll
  for (int j = 0; j < 4; j++) o4[j] = f2bf(best[j]);
  *(u16x4*)&gout[((size_t)bt * total + p) * 256 + g * 4] = o4;
}

// MFMA windowed attention: one WAVE per (b, region, head); 4 waves/block.
template<int SRC>
__global__ __launch_bounds__(256)
void attn_mfma(const u16* __restrict__ src, u16* __restrict__ fh,
               int side, int Hs, int head_base, int rep)
{
  __shared__ __align__(16) u16 sV[4][64 * 64];
  __shared__ __align__(16) u16 sP[4][64 * 64];
  const int tid = threadIdx.x;
  const int lane = tid & 63;
  const int w = tid >> 6;
  const int nreg = side * side;
  int unit = blockIdx.x * 4 + w;
  const int h = unit & 3; unit >>= 2;
  const int r = unit % nreg;
  const int b = unit / nreg;
  const int hr = r / side, wr = r - hr * side;
  const int l15 = lane & 15, l4 = lane >> 4;

  char* vb = (char*)sV[w];
  char* pb = (char*)sP[w];

  auto gidx = [&](int t, int pp, int c) -> size_t {
    const int py = pp / 7, px = pp - py * 7;
    const int yy = hr * 7 + py, xx = wr * 7 + px;
    if (SRC == 0) return ((size_t)(b * 3136 + yy * 56 + xx)) * 2304 + (size_t)(t * 768 + h * 64 + c);
    else          return ((size_t)(b * 3 + t)) * ((size_t)Hs * Hs * 256) + (size_t)(yy * Hs + xx) * 256 + h * 64 + c;
  };

  // ---- stage V (t=2), rows clamped; swizzle byte ^= ((q>>3)&3)<<5 ----
  for (int i = lane; i < 1024; i += 64) {
    const int q = i >> 4, dc = i & 15;
    const int qs = q > 48 ? 48 : q;
    const u16x4 v4 = *(const u16x4*)&src[gidx(2, qs, dc * 4)];
    *(u16x4*)(vb + ((q * 128 + dc * 8) ^ (((q >> 3) & 3) << 5))) = v4;
  }

  // ---- QK^T ----
  f32x4 s[4][4];
  #pragma unroll
  for (int i = 0; i < 4; i++)
    #pragma unroll
    for (int j = 0; j < 4; j++) s[i][j] = (f32x4)0.f;

  bf16x8 bk[4][2];
  #pragma unroll
  for (int ni = 0; ni < 4; ni++) {
    const int q = ni * 16 + l15;
    const int qs = q > 48 ? 48 : q;
    #pragma unroll
    for (int ks = 0; ks < 2; ks++)
      bk[ni][ks] = *(const bf16x8*)&src[gidx(1, qs, ks * 32 + l4 * 8)];
  }
  #pragma unroll
  for (int mi = 0; mi < 4; mi++) {
    const int p = mi * 16 + l15;
    const int ps = p > 48 ? 48 : p;
    const bf16x8 a0 = *(const bf16x8*)&src[gidx(0, ps, l4 * 8)];
    const bf16x8 a1 = *(const bf16x8*)&src[gidx(0, ps, 32 + l4 * 8)];
    #pragma unroll
    for (int ni = 0; ni < 4; ni++) {
      s[mi][ni] = __builtin_amdgcn_mfma_f32_16x16x32_bf16(a0, bk[ni][0], s[mi][ni], 0, 0, 0);
      s[mi][ni] = __builtin_amdgcn_mfma_f32_16x16x32_bf16(a1, bk[ni][1], s[mi][ni], 0, 0, 0);
    }
  }

  // ---- mask cols q>=49, in-register softmax (unnormalized P) ----
  #pragma unroll
  for (int ni = 0; ni < 4; ni++) {
    const bool bad = (ni * 16 + l15) > 48;
    #pragma unroll
    for (int mi = 0; mi < 4; mi++)
      #pragma unroll
      for (int reg = 0; reg < 4; reg++)
        s[mi][ni][reg] = bad ? -1e30f : s[mi][ni][reg];
  }

  float inv[4][4];
  #pragma unroll
  for (int mi = 0; mi < 4; mi++)
    #pragma unroll
    for (int reg = 0; reg < 4; reg++) {
      float m = fmaxf(fmaxf(s[mi][0][reg], s[mi][1][reg]), fmaxf(s[mi][2][reg], s[mi][3][reg]));
      m = fmaxf(m, __shfl_xor(m, 1));
      m = fmaxf(m, __shfl_xor(m, 2));
      m = fmaxf(m, __shfl_xor(m, 4));
      m = fmaxf(m, __shfl_xor(m, 8));
      float partial = 0.f;
      #pragma unroll
      for (int ni = 0; ni < 4; ni++) {
        const float e = __expf((s[mi][ni][reg] - m) * 0.125f);
        s[mi][ni][reg] = e;
        partial += e;
      }
      partial += __shfl_xor(partial, 1);
      partial += __shfl_xor(partial, 2);
      partial += __shfl_xor(partial, 4);
      partial += __shfl_xor(partial, 8);
      inv[mi][reg] = 1.f / partial;
    }

  // ---- P -> LDS (bf16, XOR-swizzled rows) ----
  #pragma unroll
  for (int mi = 0; mi < 4; mi++)
    #pragma unroll
    for (int ni = 0; ni < 4; ni++)
      #pragma unroll
      for (int reg = 0; reg < 4; reg++) {
        const int row = mi * 16 + l4 * 4 + reg;
        const int col = ni * 16 + l15;
        *(u16*)(pb + ((row * 128 + col * 2) ^ ((row & 7) << 4))) = f2bf(s[mi][ni][reg]);
      }
  __syncthreads();

  // ---- PV ----
  f32x4 o[4][4];
  #pragma unroll
  for (int i = 0; i < 4; i++)
    #pragma unroll
    for (int j = 0; j < 4; j++) o[i][j] = (f32x4)0.f;

  #pragma unroll
  for (int ks = 0; ks < 2; ks++) {
    bf16x8 bv[4];
    #pragma unroll
    for (int ni = 0; ni < 4; ni++)
      #pragma unroll
      for (int j = 0; j < 8; j++) {
        const int q = ks * 32 + l4 * 8 + j;
        bv[ni][j] = *(const short*)(vb + ((q * 128 + (ni * 16 + l15) * 2) ^ (((q >> 3) & 3) << 5)));
      }
    #pragma unroll
    for (int mi = 0; mi < 4; mi++) {
      const int row = mi * 16 + l15;
      const bf16x8 pa = *(const bf16x8*)(pb + ((row * 128 + (ks * 4 + l4) * 16) ^ ((row & 7) << 4)));
      #pragma unroll
      for (int ni = 0; ni < 4; ni++)
        o[mi][ni] = __builtin_amdgcn_mfma_f32_16x16x32_bf16(pa, bv[ni], o[mi][ni], 0, 0, 0);
    }
  }

  // ---- epilogue: scale by 1/sum, bf16, replicate ----
  const int head = head_base + h;
  #pragma unroll
  for (int mi = 0; mi < 4; mi++)
    #pragma unroll
    for (int reg = 0; reg < 4; reg++) {
      const int p = mi * 16 + l4 * 4 + reg;
      if (p >= 49) continue;
      const float iv = inv[mi][reg];
      u16 hv[4];
      #pragma unroll
      for (int ni = 0; ni < 4; ni++) hv[ni] = f2bf(o[mi][ni][reg] * iv);
      for (int m = 0; m < rep; m++) {
        const size_t ob = ((size_t)b * 3136 + (size_t)(m * nreg + r) * 49 + p) * 768 + head * 64 + l15;
        #pragma unroll
        for (int ni = 0; ni < 4; ni++) fh[ob + ni * 16] = hv[ni];
      }
    }
}

extern "C" void kernel_launch(void* const* d_in, const int* in_sizes, int n_in,
                              void* d_out, int out_size, void* d_ws, size_t ws_size,
                              hipStream_t stream)
{
  const float* x      = (const float*)d_in[0];
  const float* w_qkv  = (const float*)d_in[1];
  const float* w_proj = (const float*)d_in[2];
  const float* b_proj = (const float*)d_in[3];
  const float* c1w    = (const float*)d_in[4];
  const float* c1b    = (const float*)d_in[5];
  const float* c2w    = (const float*)d_in[6];
  const float* c2b    = (const float*)d_in[7];
  float* out = (float*)d_out;

  u16 *xh, *wqkvh, *wprojh, *qkvb, *g1, *g2, *fh;
  hipGetSymbolAddress((void**)&xh,     HIP_SYMBOL(g_xh));
  hipGetSymbolAddress((void**)&wqkvh,  HIP_SYMBOL(g_wqkvh));
  hipGetSymbolAddress((void**)&wprojh, HIP_SYMBOL(g_wprojh));
  hipGetSymbolAddress((void**)&qkvb,   HIP_SYMBOL(g_qkv));
  hipGetSymbolAddress((void**)&g1,     HIP_SYMBOL(g_g1));
  hipGetSymbolAddress((void**)&g2,     HIP_SYMBOL(g_g2));
  hipGetSymbolAddress((void**)&fh,     HIP_SYMBOL(g_fh));

  // 0) one-shot bf16 conversions
  cvt_bf16<<<2048, 256, 0, stream>>>(x,      xh,     50176 * 768 / 4);
  cvt_bf16<<<512,  256, 0, stream>>>(w_qkv,  wqkvh,  2304 * 768 / 4);
  cvt_bf16<<<512,  256, 0, stream>>>(w_proj, wprojh, 768 * 768 / 4);

  // 1) QKV GEMM (bf16): (50176,768)@(2304,768)^T -> qkv bf16
  gemm_lds<false, u16><<<(2304 / 128) * (50176 / 128), 256, 0, stream>>>(
      xh, wqkvh, nullptr, qkvb, 2304, 768, 2304 / 128);

  // 2) convs for scales 1 and 2 (bf16 out)
  conv_pool<<<dim3(48, 196), dim3(64, 4), 0, stream>>>(qkvb, c1w, c1b, g1, 256, 28, 1, 1, 1);
  conv_pool<<<dim3(48, 49),  dim3(64, 4), 0, stream>>>(qkvb, c2w, c2b, g2, 512, 14, 2, 2, 2);

  // 3) MFMA windowed attention per scale -> fused bf16
  attn_mfma<0><<<16 * 64 * 4 / 4, 256, 0, stream>>>(qkvb, fh, 8, 56, 0, 1);
  attn_mfma<1><<<16 * 16 * 4 / 4, 256, 0, stream>>>(g1,   fh, 4, 28, 4, 4);
  attn_mfma<1><<<16 * 4 * 4 / 4,  256, 0, stream>>>(g2,   fh, 2, 14, 8, 16);

  // 4) proj GEMM + bias -> out (f32)
  gemm_lds<true, float><<<(768 / 128) * (50176 / 128), 256, 0, stream>>>(
      fh, wprojh, b_proj, out, 768, 768, 768 / 128);
}

// Round 6
// 628.117 us; speedup vs baseline: 2.4868x; 1.1229x over previous
//
#include <hip/hip_runtime.h>

typedef __attribute__((ext_vector_type(4))) float f32x4;
typedef __attribute__((ext_vector_type(8))) short bf16x8;
typedef __attribute__((ext_vector_type(4))) unsigned short u16x4;
typedef unsigned short u16;

// Static device intermediates (BSS; fully rewritten every launch).
__device__ static u16   g_xh[(size_t)50176 * 768];     // bf16(x)            77 MB
__device__ static u16   g_wqkvh[(size_t)2304 * 768];   // bf16(w_qkv)       3.5 MB
__device__ static u16   g_wprojh[(size_t)768 * 768];   // bf16(w_proj)      1.2 MB
__device__ static u16   g_qkv[(size_t)50176 * 2304];   // qkv bf16          231 MB
__device__ static u16   g_g1[(size_t)48 * 784 * 256];  // conv1 out bf16     19 MB
__device__ static u16   g_g2[(size_t)48 * 196 * 256];  // conv2 out bf16    4.8 MB
__device__ static u16   g_fh[(size_t)50176 * 768];     // fused bf16         77 MB

static __device__ __forceinline__ u16 f2bf(float x){
  unsigned u = __float_as_uint(x);
  u += 0x7fffu + ((u >> 16) & 1u);
  return (u16)(u >> 16);
}
static __device__ __forceinline__ float bf2f(u16 h){
  return __uint_as_float(((unsigned)h) << 16);
}

// f32 -> bf16 (RNE), vectorized x4, grid-stride.
__global__ __launch_bounds__(256)
void cvt_bf16(const float* __restrict__ in, u16* __restrict__ out, int n4)
{
  int i = blockIdx.x * blockDim.x + threadIdx.x;
  const int stride = gridDim.x * blockDim.x;
  for (; i < n4; i += stride) {
    const f32x4 v = ((const f32x4*)in)[i];
    u16x4 o;
    #pragma unroll
    for (int j = 0; j < 4; j++) o[j] = f2bf(v[j]);
    ((u16x4*)out)[i] = o;
  }
}

// ---------------------------------------------------------------------------
// 256x256-tile GEMM, 8 waves (2x4), BK=32, 4 LDS buffers, counted-vmcnt
// pipeline: per K-step {STAGE(t+2); vmcnt(8); raw s_barrier; ds_read+MFMA}.
// Loads stay 2 K-steps in flight (never drained in-loop).  C = A * B^T.
//
// LDS tile layout (per 16KB operand tile, logical [256 rows][32 bf16]):
//   row-pairs packed into 128B physical rows: pr=r>>1, a=r&1, cc=c>>3;
//   16B-chunk p = (a*4+cc) ^ (pr&7);  byte = pr*128 + p*16 + (c&7)*2.
// global_load_lds writes linearly (thread tid -> byte tid*16); the SOURCE
// address is the inverse-swizzled global element (rule #21).
// ---------------------------------------------------------------------------
template<bool BIAS, typename OUT_T>
__global__ __launch_bounds__(512, 2)
void gemm256(const u16* __restrict__ A0, const u16* __restrict__ Bw,
             const float* __restrict__ bias, OUT_T* __restrict__ C,
             int N, int K, int GX)
{
  __shared__ __align__(16) char ldsb[4 * 32768];   // 4 buf x (A 16K + B 16K)
  const int tid = threadIdx.x;
  const int lane = tid & 63;
  const int w = tid >> 6;          // 0..7
  const int wm = w >> 2;           // 0..1 : row half (128 rows)
  const int wn = w & 3;            // 0..3 : col quarter (64 cols)
  const int l15 = lane & 15, l4 = lane >> 4;

  // T1 bijective XCD swizzle (m204).
  const int nwg = gridDim.x;
  const int bid = blockIdx.x;
  const int q8 = nwg >> 3, r8 = nwg & 7;
  const int xcd = bid & 7, lid = bid >> 3;
  const int swz = (xcd < r8 ? xcd * (q8 + 1) : r8 * (q8 + 1) + (xcd - r8) * q8) + lid;
  const int bn = swz % GX;
  const int bm = swz / GX;

  // ---- staging source precompute (inverse swizzle) ----
  const int sq = tid >> 3;                 // physical row within 64-row half
  const int sp = tid & 7;                  // physical chunk
  const int tt = sp ^ (sq & 7);
  const int sa = tt >> 2, scc = tt & 3;
  const int srow0 = sq * 2 + sa;           // logical row (half 0)
  const u16* a0 = A0 + (size_t)(bm * 256 + srow0) * K + scc * 8;
  const u16* a1 = A0 + (size_t)(bm * 256 + 128 + srow0) * K + scc * 8;
  const u16* b0 = Bw + (size_t)(bn * 256 + srow0) * K + scc * 8;
  const u16* b1 = Bw + (size_t)(bn * 256 + 128 + srow0) * K + scc * 8;
  const int wofs = w << 10;

  #define GLDS(srcp, ldsoff) __builtin_amdgcn_global_load_lds( \
      (__attribute__((address_space(1))) const void*)(srcp),   \
      (__attribute__((address_space(3))) void*)(ldsb + (ldsoff)), 16, 0, 0)

  auto STAGE = [&](int s) {
    const int bb = (s & 3) << 15;
    const int ko = s * 32;
    GLDS(a0 + ko, bb + wofs);
    GLDS(a1 + ko, bb + 8192 + wofs);
    GLDS(b0 + ko, bb + 16384 + wofs);
    GLDS(b1 + ko, bb + 24576 + wofs);
  };

  f32x4 acc[8][4];
  #pragma unroll
  for (int i = 0; i < 8; i++)
    #pragma unroll
    for (int j = 0; j < 4; j++) acc[i][j] = (f32x4)0.f;

  auto COMPUTE = [&](int t) {
    const char* base = ldsb + ((t & 3) << 15);
    bf16x8 bfr[4], afr[8];
    #pragma unroll
    for (int ni = 0; ni < 4; ni++) {
      const int r = wn * 64 + ni * 16 + l15;
      const int pr = r >> 1;
      const int p = (((r & 1) << 2) + l4) ^ (pr & 7);
      bfr[ni] = *(const bf16x8*)(base + 16384 + pr * 128 + p * 16);
    }
    #pragma unroll
    for (int mi = 0; mi < 8; mi++) {
      const int r = wm * 128 + mi * 16 + l15;
      const int pr = r >> 1;
      const int p = (((r & 1) << 2) + l4) ^ (pr & 7);
      afr[mi] = *(const bf16x8*)(base + pr * 128 + p * 16);
    }
    __builtin_amdgcn_s_setprio(1);
    #pragma unroll
    for (int mi = 0; mi < 8; mi++)
      #pragma unroll
      for (int ni = 0; ni < 4; ni++)
        acc[mi][ni] = __builtin_amdgcn_mfma_f32_16x16x32_bf16(afr[mi], bfr[ni], acc[mi][ni], 0, 0, 0);
    __builtin_amdgcn_s_setprio(0);
  };

  const int T = K >> 5;   // K/32 steps
  STAGE(0);
  STAGE(1);
  for (int t = 0; t < T - 2; ++t) {
    STAGE(t + 2);
    asm volatile("s_waitcnt vmcnt(8)" ::: "memory");
    __builtin_amdgcn_sched_barrier(0);
    __builtin_amdgcn_s_barrier();
    __builtin_amdgcn_sched_barrier(0);
    COMPUTE(t);
  }
  asm volatile("s_waitcnt vmcnt(4)" ::: "memory");
  __builtin_amdgcn_sched_barrier(0);
  __builtin_amdgcn_s_barrier();
  __builtin_amdgcn_sched_barrier(0);
  COMPUTE(T - 2);
  asm volatile("s_waitcnt vmcnt(0)" ::: "memory");
  __builtin_amdgcn_sched_barrier(0);
  __builtin_amdgcn_s_barrier();
  __builtin_amdgcn_sched_barrier(0);
  COMPUTE(T - 1);
  #undef GLDS

  // ---- epilogue ----
  #pragma unroll
  for (int mi = 0; mi < 8; mi++)
    #pragma unroll
    for (int ni = 0; ni < 4; ni++) {
      const int col = bn * 256 + wn * 64 + ni * 16 + l15;
      const float bv = BIAS ? bias[col] : 0.f;
      #pragma unroll
      for (int reg = 0; reg < 4; reg++) {
        const int row = bm * 256 + wm * 128 + mi * 16 + (l4 << 2) + reg;
        const float val = acc[mi][ni][reg] + bv;
        if constexpr (sizeof(OUT_T) == 2) C[(size_t)row * N + col] = (OUT_T)f2bf(val);
        else                              C[(size_t)row * N + col] = val;
      }
    }
}

// Fused grouped conv3x3 (groups=64, 4in/4out) + bias + 2x2 maxpool -> bf16.
__global__ __launch_bounds__(256)
void conv_pool(const u16* __restrict__ qkv, const float* __restrict__ wsrc,
               const float* __restrict__ bias, u16* __restrict__ gout,
               int chan0, int Pout, int st, int pd, int dl)
{
  __shared__ float wl[64 * 145];
  const int g = threadIdx.x;
  const int ty = threadIdx.y;
  const int tid = ty * 64 + g;
  for (int i = tid; i < 9216; i += 256) {
    const int oc = i / 36, rem = i - oc * 36;
    wl[(oc >> 2) * 145 + (oc & 3) * 36 + rem] = wsrc[i];
  }
  __syncthreads();

  const int bt = blockIdx.x;
  const int b = bt / 3, t = bt - b * 3;
  const int total = Pout * Pout;
  const int p = blockIdx.y * 4 + ty;
  if (p >= total) return;
  const int y = p / Pout, x = p - y * Pout;

  const f32x4 bias4 = *(const f32x4*)&bias[g * 4];
  f32x4 best;
  #pragma unroll
  for (int j = 0; j < 4; j++) best[j] = -3.4e38f;
  const float* wg = &wl[g * 145];

  #pragma unroll
  for (int dy = 0; dy < 2; dy++)
    #pragma unroll
    for (int dx = 0; dx < 2; dx++) {
      const int py = 2 * y + dy, px = 2 * x + dx;
      f32x4 c4 = bias4;
      #pragma unroll
      for (int ky = 0; ky < 3; ky++) {
        const int iy = py * st - pd + ky * dl;
        if (iy < 0 || iy >= 56) continue;
        #pragma unroll
        for (int kx = 0; kx < 3; kx++) {
          const int ix = px * st - pd + kx * dl;
          if (ix < 0 || ix >= 56) continue;
          const u16x4 in4 = *(const u16x4*)&qkv[(size_t)(b * 3136 + iy * 56 + ix) * 2304 + t * 768 + chan0 + g * 4];
          const float f0 = bf2f(in4[0]), f1 = bf2f(in4[1]), f2 = bf2f(in4[2]), f3 = bf2f(in4[3]);
          #pragma unroll
          for (int oc = 0; oc < 4; oc++) {
            const float* wp = &wg[oc * 36 + ky * 3 + kx];
            c4[oc] += f0 * wp[0] + f1 * wp[9] + f2 * wp[18] + f3 * wp[27];
          }
        }
      }
      #pragma unroll
      for (int j = 0; j < 4; j++) best[j] = fmaxf(best[j], c4[j]);
    }
  u16x4 o4;
  #pragma unroll
  for (int j = 0; j < 4; j++) o4[j] = f2bf(best[j]);
  *(u16x4*)&gout[((size_t)bt * total + p) * 256 + g * 4] = o4;
}

// MFMA windowed attention: one WAVE per (b, region, head); 4 waves/block.
template<int SRC>
__global__ __launch_bounds__(256)
void attn_mfma(const u16* __restrict__ src, u16* __restrict__ fh,
               int side, int Hs, int head_base, int rep)
{
  __shared__ __align__(16) u16 sV[4][64 * 64];
  __shared__ __align__(16) u16 sP[4][64 * 64];
  const int tid = threadIdx.x;
  const int lane = tid & 63;
  const int w = tid >> 6;
  const int nreg = side * side;
  int unit = blockIdx.x * 4 + w;
  const int h = unit & 3; unit >>= 2;
  const int r = unit % nreg;
  const int b = unit / nreg;
  const int hr = r / side, wr = r - hr * side;
  const int l15 = lane & 15, l4 = lane >> 4;

  char* vb = (char*)sV[w];
  char* pb = (char*)sP[w];

  auto gidx = [&](int t, int pp, int c) -> size_t {
    const int py = pp / 7, px = pp - py * 7;
    const int yy = hr * 7 + py, xx = wr * 7 + px;
    if (SRC == 0) return ((size_t)(b * 3136 + yy * 56 + xx)) * 2304 + (size_t)(t * 768 + h * 64 + c);
    else          return ((size_t)(b * 3 + t)) * ((size_t)Hs * Hs * 256) + (size_t)(yy * Hs + xx) * 256 + h * 64 + c;
  };

  // ---- stage V (t=2), rows clamped; swizzle byte ^= ((q>>3)&3)<<5 ----
  for (int i = lane; i < 1024; i += 64) {
    const int q = i >> 4, dc = i & 15;
    const int qs = q > 48 ? 48 : q;
    const u16x4 v4 = *(const u16x4*)&src[gidx(2, qs, dc * 4)];
    *(u16x4*)(vb + ((q * 128 + dc * 8) ^ (((q >> 3) & 3) << 5))) = v4;
  }

  // ---- QK^T ----
  f32x4 s[4][4];
  #pragma unroll
  for (int i = 0; i < 4; i++)
    #pragma unroll
    for (int j = 0; j < 4; j++) s[i][j] = (f32x4)0.f;

  bf16x8 bk[4][2];
  #pragma unroll
  for (int ni = 0; ni < 4; ni++) {
    const int q = ni * 16 + l15;
    const int qs = q > 48 ? 48 : q;
    #pragma unroll
    for (int ks = 0; ks < 2; ks++)
      bk[ni][ks] = *(const bf16x8*)&src[gidx(1, qs, ks * 32 + l4 * 8)];
  }
  #pragma unroll
  for (int mi = 0; mi < 4; mi++) {
    const int p = mi * 16 + l15;
    const int ps = p > 48 ? 48 : p;
    const bf16x8 a0 = *(const bf16x8*)&src[gidx(0, ps, l4 * 8)];
    const bf16x8 a1 = *(const bf16x8*)&src[gidx(0, ps, 32 + l4 * 8)];
    #pragma unroll
    for (int ni = 0; ni < 4; ni++) {
      s[mi][ni] = __builtin_amdgcn_mfma_f32_16x16x32_bf16(a0, bk[ni][0], s[mi][ni], 0, 0, 0);
      s[mi][ni] = __builtin_amdgcn_mfma_f32_16x16x32_bf16(a1, bk[ni][1], s[mi][ni], 0, 0, 0);
    }
  }

  // ---- mask cols q>=49, in-register softmax (unnormalized P) ----
  #pragma unroll
  for (int ni = 0; ni < 4; ni++) {
    const bool bad = (ni * 16 + l15) > 48;
    #pragma unroll
    for (int mi = 0; mi < 4; mi++)
      #pragma unroll
      for (int reg = 0; reg < 4; reg++)
        s[mi][ni][reg] = bad ? -1e30f : s[mi][ni][reg];
  }

  float inv[4][4];
  #pragma unroll
  for (int mi = 0; mi < 4; mi++)
    #pragma unroll
    for (int reg = 0; reg < 4; reg++) {
      float m = fmaxf(fmaxf(s[mi][0][reg], s[mi][1][reg]), fmaxf(s[mi][2][reg], s[mi][3][reg]));
      m = fmaxf(m, __shfl_xor(m, 1));
      m = fmaxf(m, __shfl_xor(m, 2));
      m = fmaxf(m, __shfl_xor(m, 4));
      m = fmaxf(m, __shfl_xor(m, 8));
      float partial = 0.f;
      #pragma unroll
      for (int ni = 0; ni < 4; ni++) {
        const float e = __expf((s[mi][ni][reg] - m) * 0.125f);
        s[mi][ni][reg] = e;
        partial += e;
      }
      partial += __shfl_xor(partial, 1);
      partial += __shfl_xor(partial, 2);
      partial += __shfl_xor(partial, 4);
      partial += __shfl_xor(partial, 8);
      inv[mi][reg] = 1.f / partial;
    }

  // ---- P -> LDS (bf16, XOR-swizzled rows) ----
  #pragma unroll
  for (int mi = 0; mi < 4; mi++)
    #pragma unroll
    for (int ni = 0; ni < 4; ni++)
      #pragma unroll
      for (int reg = 0; reg < 4; reg++) {
        const int row = mi * 16 + l4 * 4 + reg;
        const int col = ni * 16 + l15;
        *(u16*)(pb + ((row * 128 + col * 2) ^ ((row & 7) << 4))) = f2bf(s[mi][ni][reg]);
      }
  __syncthreads();

  // ---- PV ----
  f32x4 o[4][4];
  #pragma unroll
  for (int i = 0; i < 4; i++)
    #pragma unroll
    for (int j = 0; j < 4; j++) o[i][j] = (f32x4)0.f;

  #pragma unroll
  for (int ks = 0; ks < 2; ks++) {
    bf16x8 bv[4];
    #pragma unroll
    for (int ni = 0; ni < 4; ni++)
      #pragma unroll
      for (int j = 0; j < 8; j++) {
        const int q = ks * 32 + l4 * 8 + j;
        bv[ni][j] = *(const short*)(vb + ((q * 128 + (ni * 16 + l15) * 2) ^ (((q >> 3) & 3) << 5)));
      }
    #pragma unroll
    for (int mi = 0; mi < 4; mi++) {
      const int row = mi * 16 + l15;
      const bf16x8 pa = *(const bf16x8*)(pb + ((row * 128 + (ks * 4 + l4) * 16) ^ ((row & 7) << 4)));
      #pragma unroll
      for (int ni = 0; ni < 4; ni++)
        o[mi][ni] = __builtin_amdgcn_mfma_f32_16x16x32_bf16(pa, bv[ni], o[mi][ni], 0, 0, 0);
    }
  }

  // ---- epilogue: scale by 1/sum, bf16, replicate ----
  const int head = head_base + h;
  #pragma unroll
  for (int mi = 0; mi < 4; mi++)
    #pragma unroll
    for (int reg = 0; reg < 4; reg++) {
      const int p = mi * 16 + l4 * 4 + reg;
      if (p >= 49) continue;
      const float iv = inv[mi][reg];
      u16 hv[4];
      #pragma unroll
      for (int ni = 0; ni < 4; ni++) hv[ni] = f2bf(o[mi][ni][reg] * iv);
      for (int m = 0; m < rep; m++) {
        const size_t ob = ((size_t)b * 3136 + (size_t)(m * nreg + r) * 49 + p) * 768 + head * 64 + l15;
        #pragma unroll
        for (int ni = 0; ni < 4; ni++) fh[ob + ni * 16] = hv[ni];
      }
    }
}

extern "C" void kernel_launch(void* const* d_in, const int* in_sizes, int n_in,
                              void* d_out, int out_size, void* d_ws, size_t ws_size,
                              hipStream_t stream)
{
  const float* x      = (const float*)d_in[0];
  const float* w_qkv  = (const float*)d_in[1];
  const float* w_proj = (const float*)d_in[2];
  const float* b_proj = (const float*)d_in[3];
  const float* c1w    = (const float*)d_in[4];
  const float* c1b    = (const float*)d_in[5];
  const float* c2w    = (const float*)d_in[6];
  const float* c2b    = (const float*)d_in[7];
  float* out = (float*)d_out;

  u16 *xh, *wqkvh, *wprojh, *qkvb, *g1, *g2, *fh;
  hipGetSymbolAddress((void**)&xh,     HIP_SYMBOL(g_xh));
  hipGetSymbolAddress((void**)&wqkvh,  HIP_SYMBOL(g_wqkvh));
  hipGetSymbolAddress((void**)&wprojh, HIP_SYMBOL(g_wprojh));
  hipGetSymbolAddress((void**)&qkvb,   HIP_SYMBOL(g_qkv));
  hipGetSymbolAddress((void**)&g1,     HIP_SYMBOL(g_g1));
  hipGetSymbolAddress((void**)&g2,     HIP_SYMBOL(g_g2));
  hipGetSymbolAddress((void**)&fh,     HIP_SYMBOL(g_fh));

  // 0) one-shot bf16 conversions
  cvt_bf16<<<2048, 256, 0, stream>>>(x,      xh,     50176 * 768 / 4);
  cvt_bf16<<<512,  256, 0, stream>>>(w_qkv,  wqkvh,  2304 * 768 / 4);
  cvt_bf16<<<512,  256, 0, stream>>>(w_proj, wprojh, 768 * 768 / 4);

  // 1) QKV GEMM (bf16): (50176,768)@(2304,768)^T -> qkv bf16
  gemm256<false, u16><<<(50176 / 256) * (2304 / 256), 512, 0, stream>>>(
      xh, wqkvh, nullptr, qkvb, 2304, 768, 2304 / 256);

  // 2) convs for scales 1 and 2 (bf16 out)
  conv_pool<<<dim3(48, 196), dim3(64, 4), 0, stream>>>(qkvb, c1w, c1b, g1, 256, 28, 1, 1, 1);
  conv_pool<<<dim3(48, 49),  dim3(64, 4), 0, stream>>>(qkvb, c2w, c2b, g2, 512, 14, 2, 2, 2);

  // 3) MFMA windowed attention per scale -> fused bf16
  attn_mfma<0><<<16 * 64 * 4 / 4, 256, 0, stream>>>(qkvb, fh, 8, 56, 0, 1);
  attn_mfma<1><<<16 * 16 * 4 / 4, 256, 0, stream>>>(g1,   fh, 4, 28, 4, 4);
  attn_mfma<1><<<16 * 4 * 4 / 4,  256, 0, stream>>>(g2,   fh, 2, 14, 8, 16);

  // 4) proj GEMM + bias -> out (f32)
  gemm256<true, float><<<(50176 / 256) * (768 / 256), 512, 0, stream>>>(
      fh, wprojh, b_proj, out, 768, 768, 768 / 256);
}